// Round 9
// baseline (3331.910 us; speedup 1.0000x reference)
//
#include <hip/hip_runtime.h>
#include <math.h>

#define NTOT 131072   // B*N

typedef unsigned short ushort_t;
typedef __attribute__((ext_vector_type(8))) short short8;
typedef __attribute__((ext_vector_type(4))) short short4_t;
typedef __attribute__((ext_vector_type(4))) float f32x4;

__device__ __forceinline__ float bf2f(ushort_t u){
  unsigned int v = ((unsigned int)u) << 16; float f;
  __builtin_memcpy(&f, &v, 4); return f;
}
__device__ __forceinline__ ushort_t f2bf(float f){
  unsigned int x; __builtin_memcpy(&x, &f, 4);
  x = (x + 0x7fffu + ((x >> 16) & 1u)) >> 16;
  return (ushort_t)x;
}
__device__ __forceinline__ void gld16(const void* g, void* l){
  __builtin_amdgcn_global_load_lds((const __attribute__((address_space(1))) void*)g,
                                   (__attribute__((address_space(3))) void*)l, 16, 0, 0);
}
// split f32 -> hi/lo bf16 and store into packed activation row (stride 512)
__device__ __forceinline__ void store_hl(ushort_t* row, int col, float v){
  ushort_t hi = f2bf(v);
  row[col] = hi;
  row[col + 256] = f2bf(v - bf2f(hi));
}

// ---------------- weight packing: hi/lo planes ----------------
__global__ __launch_bounds__(256) void packhl_k(const float* __restrict__ src, ushort_t* __restrict__ dst, int n){
  int i = blockIdx.x*256 + threadIdx.x;
  if (i < n){
    float v = src[i];
    ushort_t hi = f2bf(v);
    dst[i] = hi;
    dst[n + i] = f2bf(v - bf2f(hi));
  }
}

// ---------------- KV prep: LN(z_multi) -> K, V (f32, [b][m][256]) ----------------
__global__ __launch_bounds__(256) void prepkv_f(const float* __restrict__ zm, const float* __restrict__ inW,
    const float* __restrict__ inb, const float* __restrict__ g, const float* __restrict__ bv,
    float* __restrict__ Kf, float* __restrict__ Vf){
  __shared__ float zr[256];
  __shared__ float red[256];
  int bm = blockIdx.x;
  int t = threadIdx.x;
  float v = zm[(size_t)bm*256 + t];
  red[t] = v; __syncthreads();
  for (int s = 128; s > 0; s >>= 1){ if (t < s) red[t] += red[t+s]; __syncthreads(); }
  float mu = red[0] * (1.f/256.f); __syncthreads();
  red[t] = (v-mu)*(v-mu); __syncthreads();
  for (int s = 128; s > 0; s >>= 1){ if (t < s) red[t] += red[t+s]; __syncthreads(); }
  float var = red[0] * (1.f/256.f);
  float rsd = rsqrtf(var + 1e-5f);
  __syncthreads();
  zr[t] = (v - mu) * rsd * g[t] + bv[t];
  __syncthreads();
  float accK = inb[256+t], accV = inb[512+t];
  const float* wk = inW + (size_t)(256+t)*256;
  const float* wv = inW + (size_t)(512+t)*256;
  for (int d = 0; d < 256; d += 4){
    float4 a = *(const float4*)(zr + d);
    float4 k4 = *(const float4*)(wk + d);
    float4 v4 = *(const float4*)(wv + d);
    accK += a.x*k4.x + a.y*k4.y + a.z*k4.z + a.w*k4.w;
    accV += a.x*v4.x + a.y*v4.y + a.z*v4.z + a.w*v4.w;
  }
  Kf[(size_t)bm*256 + t] = accK;
  Vf[(size_t)bm*256 + t] = accV;
}

// ---------------- coord MLP first layer: GELU, packed hi/lo out ----------------
__global__ __launch_bounds__(256) void hidden_h(const float* __restrict__ coords, const float* __restrict__ W1,
    const float* __restrict__ b1, ushort_t* __restrict__ out, int pt0){
  int h = threadIdx.x; int p0 = blockIdx.x*4;
  float w0 = W1[h*2], w1 = W1[h*2+1], bb = b1[h];
  #pragma unroll
  for (int pp = 0; pp < 4; ++pp){
    size_t gpt = (size_t)(pt0 + p0 + pp);
    float x = coords[gpt*2], y = coords[gpt*2+1];
    float v = x*w0 + y*w1 + bb;
    float gl = 0.5f * v * (1.f + erff(v * 0.70710678118654752f));
    store_hl(out + (size_t)(p0+pp)*512, h, gl);
  }
}

// ---------------- 3-term hi/lo MFMA GEMM, packed A in / packed out ----------------
// out[row][col] = sum_k A[row][k]*W[col][k] (+bias); A packed [row][hi256|lo256],
// W packed bf16 hi plane [256][256] then lo plane.
// EPI 0: plain  1: LayerNorm  2: multiply gabor basis computed in epilogue.
__device__ __forceinline__ void stage_w32(const ushort_t* Wbase, int oc, ushort_t* dsth, ushort_t* dstl, int w, int lane){
  #pragma unroll
  for (int part = 0; part < 2; ++part){
    const char* src0 = (const char*)(Wbase + part*65536);
    char* dst = (char*)(part ? dstl : dsth);
    #pragma unroll
    for (int i = 0; i < 4; ++i){
      int flat = ((w*4+i)*64 + lane)*16;
      int row = flat >> 9, kb = flat & 511;
      int skb = kb ^ ((row & 31) << 4);
      gld16(src0 + (size_t)(oc*32+row)*512 + skb, dst + (size_t)(w*4+i)*1024);
    }
  }
}

__device__ __forceinline__ void load_frags(const ushort_t* Ar, short8* ah, short8* al, int q4){
  #pragma unroll
  for (int kc = 0; kc < 8; ++kc){
    ah[kc] = *(const short8*)(Ar + kc*32 + q4*8);
    al[kc] = *(const short8*)(Ar + 256 + kc*32 + q4*8);
  }
}

template<int EPI, int NPASS>
__global__ __launch_bounds__(256) void gemm4_k(const ushort_t* __restrict__ A0,
    const ushort_t* __restrict__ A1, const ushort_t* __restrict__ W0,
    const ushort_t* __restrict__ W1, const float* __restrict__ bias,
    const float* __restrict__ lng, const float* __restrict__ lnb,
    const float* __restrict__ coords, const float* __restrict__ gW,
    const float* __restrict__ gb, const float* __restrict__ gmu,
    const float* __restrict__ gg, int pt0g, int fidx,
    ushort_t* __restrict__ outp){
  __shared__ ushort_t Whs[2][32*256];
  __shared__ ushort_t Wls[2][32*256];
  const int tid = threadIdx.x, lane = tid & 63, w = tid >> 6;
  const int r16 = lane & 15, q4 = lane >> 4;
  const int row0 = blockIdx.x * 64;
  const size_t arow = (size_t)(row0 + w*16 + r16);

  short8 ah[8], al[8];
  load_frags(A0 + arow*512, ah, al, q4);
  stage_w32(W0, 0, Whs[0], Wls[0], w, lane);

  f32x4 acc[16];
  #pragma unroll
  for (int i = 0; i < 16; ++i) acc[i] = (f32x4){0.f,0.f,0.f,0.f};
  __syncthreads();

  constexpr int TCH = NPASS*8;
  for (int t = 0; t < TCH; ++t){
    const int buf = t & 1;
    if (t + 1 < TCH){
      const int tn = t + 1;
      stage_w32((tn >= 8) ? W1 : W0, tn & 7, Whs[tn&1], Wls[tn&1], w, lane);
    }
    if constexpr (NPASS == 2){
      if (t == 8) load_frags(A1 + arow*512, ah, al, q4);
    }
    const int oc = t & 7;
    const char* Bh = (const char*)Whs[buf];
    const char* Bl = (const char*)Wls[buf];
    #pragma unroll
    for (int kc = 0; kc < 8; ++kc){
      const int koff = (kc*32 + q4*8)*2;
      #pragma unroll
      for (int cg = 0; cg < 2; ++cg){
        const int wrow = cg*16 + r16;
        const int off = koff ^ ((wrow & 31) << 4);
        short8 bh = *(const short8*)(Bh + (size_t)wrow*512 + off);
        short8 bl = *(const short8*)(Bl + (size_t)wrow*512 + off);
        f32x4 a_ = acc[oc*2+cg];
        a_ = __builtin_amdgcn_mfma_f32_16x16x32_bf16(ah[kc], bh, a_, 0, 0, 0);
        a_ = __builtin_amdgcn_mfma_f32_16x16x32_bf16(al[kc], bh, a_, 0, 0, 0);
        a_ = __builtin_amdgcn_mfma_f32_16x16x32_bf16(ah[kc], bl, a_, 0, 0, 0);
        acc[oc*2+cg] = a_;
      }
    }
    __syncthreads();
  }

  const int crow = row0 + w*16 + q4*4;
  if (bias){
    #pragma unroll
    for (int idx = 0; idx < 16; ++idx){
      const int col = (idx>>1)*32 + (idx&1)*16 + r16;
      const float bb = bias[col];
      #pragma unroll
      for (int r = 0; r < 4; ++r) acc[idx][r] += bb;
    }
  }
  if constexpr (EPI == 1){
    float mu[4], rs[4];
    #pragma unroll
    for (int r = 0; r < 4; ++r){
      float s = 0.f, s2 = 0.f;
      #pragma unroll
      for (int idx = 0; idx < 16; ++idx){ float v = acc[idx][r]; s += v; s2 += v*v; }
      #pragma unroll
      for (int m = 1; m < 16; m <<= 1){ s += __shfl_xor(s, m); s2 += __shfl_xor(s2, m); }
      float mean = s * (1.f/256.f);
      float var = s2 * (1.f/256.f) - mean*mean;
      mu[r] = mean; rs[r] = rsqrtf(var + 1e-5f);
    }
    #pragma unroll
    for (int idx = 0; idx < 16; ++idx){
      const int col = (idx>>1)*32 + (idx&1)*16 + r16;
      const float gv = lng[col], bv = lnb[col];
      #pragma unroll
      for (int r = 0; r < 4; ++r){
        float v = (acc[idx][r] - mu[r]) * rs[r] * gv + bv;
        store_hl(outp + (size_t)(crow + r)*512, col, v);
      }
    }
  } else if constexpr (EPI == 2){
    float xs[4], ys[4], xx[4];
    #pragma unroll
    for (int r = 0; r < 4; ++r){
      size_t gp = (size_t)(pt0g + crow + r);
      float x = coords[gp*2], y = coords[gp*2+1];
      xs[r] = x; ys[r] = y; xx[r] = x*x + y*y;
    }
    #pragma unroll
    for (int idx = 0; idx < 16; ++idx){
      const int col = (idx>>1)*32 + (idx&1)*16 + r16;
      const int o = fidx*256 + col;
      const float w0 = gW[o*2], w1 = gW[o*2+1];
      const float m0 = gmu[o*2], m1 = gmu[o*2+1];
      const float bb = gb[o], ga = gg[o];
      const float mm = m0*m0 + m1*m1;
      #pragma unroll
      for (int r = 0; r < 4; ++r){
        float D = xx[r] + mm - 2.f*(xs[r]*m0 + ys[r]*m1);
        float bas = sinf(xs[r]*w0 + ys[r]*w1 + bb) * expf(-0.5f * D * ga);
        store_hl(outp + (size_t)(crow + r)*512, col, acc[idx][r] * bas);
      }
    }
  } else {
    #pragma unroll
    for (int idx = 0; idx < 16; ++idx){
      const int col = (idx>>1)*32 + (idx&1)*16 + r16;
      #pragma unroll
      for (int r = 0; r < 4; ++r)
        store_hl(outp + (size_t)(crow + r)*512, col, acc[idx][r]);
    }
  }
}

// ---------------- attention: two-pass VALU, K in LDS (64KB), V global broadcast ----------------
// Block: 512 threads = 64 points x 8 heads. Thread = (p = tid&63, h = tid>>6).
__global__ __launch_bounds__(512) void attn4_k(const ushort_t* __restrict__ Q2,
    const float* __restrict__ Kf, const float* __restrict__ Vf,
    ushort_t* __restrict__ ctx, int pt0){
  __shared__ float Kl[64*256];
  const int tid = threadIdx.x;
  const int p = tid & 63, h = tid >> 6;
  const int prow0 = blockIdx.x * 64;
  const int b = (pt0 + prow0) >> 14;
  {
    const float4* Kg = (const float4*)(Kf + (size_t)b*64*256);
    float4* Klv = (float4*)Kl;
    #pragma unroll
    for (int i = 0; i < 8; ++i){
      int ix = i*512 + tid;
      Klv[ix] = Kg[ix];
    }
  }
  __syncthreads();

  const ushort_t* Qr = Q2 + (size_t)(prow0 + p)*512 + h*32;
  const float scale = 0.17677669529663687f;
  float q[32];
  #pragma unroll
  for (int g = 0; g < 4; ++g){
    short8 h8 = *(const short8*)(Qr + g*8);
    short8 l8 = *(const short8*)(Qr + 256 + g*8);
    #pragma unroll
    for (int j = 0; j < 8; ++j)
      q[g*8+j] = bf2f((ushort_t)h8[j]) + bf2f((ushort_t)l8[j]);
  }
  // pass 1: row max (4 independent partial sums for ILP)
  float mx = -1e30f;
  #pragma unroll 2
  for (int m = 0; m < 64; ++m){
    const float* Kr = Kl + m*256 + h*32;
    float ss0=0.f, ss1=0.f, ss2=0.f, ss3=0.f;
    #pragma unroll
    for (int k4 = 0; k4 < 8; ++k4){
      float4 kv = *(const float4*)(Kr + k4*4);
      const float* qq = q + k4*4;
      float d = qq[0]*kv.x + qq[1]*kv.y + qq[2]*kv.z + qq[3]*kv.w;
      if ((k4 & 3) == 0) ss0 += d; else if ((k4 & 3) == 1) ss1 += d;
      else if ((k4 & 3) == 2) ss2 += d; else ss3 += d;
    }
    float s = (ss0 + ss1) + (ss2 + ss3);
    mx = fmaxf(mx, s*scale);
  }
  // pass 2: exp, sum, PV (V read from global, wave-uniform -> broadcast)
  const float* Vb = Vf + (size_t)b*64*256 + h*32;
  float o[32];
  #pragma unroll
  for (int d = 0; d < 32; ++d) o[d] = 0.f;
  float sum = 0.f;
  #pragma unroll 2
  for (int m = 0; m < 64; ++m){
    const float* Kr = Kl + m*256 + h*32;
    float ss0=0.f, ss1=0.f, ss2=0.f, ss3=0.f;
    #pragma unroll
    for (int k4 = 0; k4 < 8; ++k4){
      float4 kv = *(const float4*)(Kr + k4*4);
      const float* qq = q + k4*4;
      float d = qq[0]*kv.x + qq[1]*kv.y + qq[2]*kv.z + qq[3]*kv.w;
      if ((k4 & 3) == 0) ss0 += d; else if ((k4 & 3) == 1) ss1 += d;
      else if ((k4 & 3) == 2) ss2 += d; else ss3 += d;
    }
    float s = (ss0 + ss1) + (ss2 + ss3);
    float pe = __expf(s*scale - mx);
    sum += pe;
    const float* Vr = Vb + (size_t)m*256;
    #pragma unroll
    for (int d4 = 0; d4 < 32; d4 += 4){
      float4 vv = *(const float4*)(Vr + d4);
      o[d4] += pe*vv.x; o[d4+1] += pe*vv.y; o[d4+2] += pe*vv.z; o[d4+3] += pe*vv.w;
    }
  }
  const float inv = 1.f / sum;
  ushort_t* Cr = ctx + (size_t)(prow0 + p)*512 + h*32;
  #pragma unroll
  for (int d = 0; d < 32; ++d){
    float cv = o[d]*inv;
    ushort_t hi = f2bf(cv);
    Cr[d] = hi;
    Cr[d + 256] = f2bf(cv - bf2f(hi));
  }
}

// ---------------- fin GEMM (36x256, f32) + irfft head, packed X in ----------------
__global__ __launch_bounds__(256) void fin_h(const ushort_t* __restrict__ X, const float* __restrict__ fW,
    const float* __restrict__ fb, float* __restrict__ outp, int pt0){
  __shared__ float Xl[64][260];
  __shared__ float s36p[64][4][37];
  __shared__ float ctab[7][16];
  __shared__ float stab[7][16];
  const int tid = threadIdx.x;
  const int row0 = blockIdx.x * 64;
  if (tid < 112){
    int f = tid >> 4, t = tid & 15;
    float a = 3.14159265358979323846f * (float)((f+1)*t) / 8.f;
    float s, c; sincosf(a, &s, &c);
    ctab[f][t] = c; stab[f][t] = s;
  }
  #pragma unroll
  for (int i = 0; i < 16; ++i){
    int r = i*4 + (tid >> 6);
    int c4 = (tid & 63)*4;
    const ushort_t* Xr = X + (size_t)(row0 + r)*512 + c4;
    short4_t h4 = *(const short4_t*)(Xr);
    short4_t l4 = *(const short4_t*)(Xr + 256);
    float4 v;
    v.x = bf2f((ushort_t)h4[0]) + bf2f((ushort_t)l4[0]);
    v.y = bf2f((ushort_t)h4[1]) + bf2f((ushort_t)l4[1]);
    v.z = bf2f((ushort_t)h4[2]) + bf2f((ushort_t)l4[2]);
    v.w = bf2f((ushort_t)h4[3]) + bf2f((ushort_t)l4[3]);
    *(float4*)(&Xl[r][c4]) = v;
  }
  __syncthreads();
  {
    const int p = tid & 63, g = tid >> 6;
    float xs[64];
    #pragma unroll
    for (int k4 = 0; k4 < 64; k4 += 4){
      float4 xv = *(const float4*)(&Xl[p][g*64 + k4]);
      xs[k4] = xv.x; xs[k4+1] = xv.y; xs[k4+2] = xv.z; xs[k4+3] = xv.w;
    }
    #pragma unroll
    for (int c = 0; c < 36; ++c){
      const float* Wr = fW + (size_t)c*256 + g*64;
      float s = 0.f;
      #pragma unroll
      for (int k4 = 0; k4 < 64; k4 += 4){
        float4 wv = *(const float4*)(Wr + k4);
        s += xs[k4]*wv.x + xs[k4+1]*wv.y + xs[k4+2]*wv.z + xs[k4+3]*wv.w;
      }
      s36p[p][g][c] = s;
    }
  }
  __syncthreads();

  const int pl = tid & 63, tg = tid >> 6;
  const int gpt = pt0 + row0 + pl;
  const int b = gpt >> 14; const int n = gpt & 16383;
  float R[36];
  #pragma unroll
  for (int i = 0; i < 36; ++i)
    R[i] = s36p[pl][0][i] + s36p[pl][1][i] + s36p[pl][2][i] + s36p[pl][3][i] + fb[i];
  #pragma unroll
  for (int tt = 0; tt < 4; ++tt){
    int t = tg*4 + tt;
    float o0 = 0.f, o1 = 0.f;
    #pragma unroll
    for (int c = 0; c < 2; ++c){
      float v = R[c*2] + ((t & 1) ? -R[32 + c*2] : R[32 + c*2]);
      #pragma unroll
      for (int f = 1; f < 8; ++f){
        v += 2.f * (R[f*4 + c*2] * ctab[f-1][t] - R[f*4 + c*2 + 1] * stab[f-1][t]);
      }
      v *= 0.25f;
      if (c == 0) o0 = v; else o1 = v;
    }
    float2 wv; wv.x = o0; wv.y = o1;
    *(float2*)(outp + ((size_t)(b*16 + t)*16384 + n)*2) = wv;
  }
}

// ---------------- host ----------------
extern "C" void kernel_launch(void* const* d_in, const int* in_sizes, int n_in,
                              void* d_out, int out_size, void* d_ws, size_t ws_size,
                              hipStream_t stream){
  const float* z_multi=(const float*)d_in[0];
  const float* coords =(const float*)d_in[1];
  const float* gW =(const float*)d_in[2];
  const float* gb =(const float*)d_in[3];
  const float* gmu=(const float*)d_in[4];
  const float* gg =(const float*)d_in[5];
  const float* n1W=(const float*)d_in[6];
  const float* n1b=(const float*)d_in[7];
  const float* n2W=(const float*)d_in[8];
  const float* qpW1=(const float*)d_in[9];
  const float* qpb1=(const float*)d_in[10];
  const float* qpW2=(const float*)d_in[11];
  const float* qpb2=(const float*)d_in[12];
  const float* inW=(const float*)d_in[13];
  const float* inb=(const float*)d_in[14];
  const float* outW=(const float*)d_in[15];
  const float* outb=(const float*)d_in[16];
  const float* lnqg=(const float*)d_in[17];
  const float* lnqb=(const float*)d_in[18];
  const float* lnkg=(const float*)d_in[19];
  const float* lnkb=(const float*)d_in[20];
  const float* finW=(const float*)d_in[21];
  const float* finb=(const float*)d_in[22];
  float* outp=(float*)d_out;
  char* ws=(char*)d_ws;

  ushort_t* Wqp2=(ushort_t*)(ws + 0);         // 262144 B each (hi+lo planes)
  ushort_t* Wq  =(ushort_t*)(ws + 262144);
  ushort_t* Wout=(ushort_t*)(ws + 524288);
  ushort_t* Wn2 =(ushort_t*)(ws + 786432);    // 5 x 262144 -> ends 2097152
  ushort_t* Wn1 =(ushort_t*)(ws + 2097152);   // 4 x 262144 -> ends 3145728
  float* Kf = (float*)(ws + 3145728);         // 512 KB
  float* Vf = (float*)(ws + 3670016);         // 512 KB
  const size_t BASE = 4194304;
  size_t avail = (ws_size > BASE) ? (ws_size - BASE) : 0;
  long long ncl = (long long)(avail / 3072) & ~127LL;
  if (ncl < 128) ncl = 128;
  if (ncl > NTOT) ncl = NTOT;
  const int NC = (int)ncl;
  ushort_t* S0 = (ushort_t*)(ws + BASE);
  ushort_t* S1 = S0 + (size_t)NC*512;
  ushort_t* S2 = S1 + (size_t)NC*512;

  packhl_k<<<256,256,0,stream>>>(qpW2, Wqp2, 65536);
  packhl_k<<<256,256,0,stream>>>(inW,  Wq,   65536);
  packhl_k<<<256,256,0,stream>>>(outW, Wout, 65536);
  for (int l = 0; l < 5; ++l)
    packhl_k<<<256,256,0,stream>>>(n2W + (size_t)l*65536, Wn2 + (size_t)l*131072, 65536);
  for (int l = 0; l < 4; ++l)
    packhl_k<<<256,256,0,stream>>>(n1W + (size_t)l*65536, Wn1 + (size_t)l*131072, 65536);
  prepkv_f<<<512,256,0,stream>>>(z_multi, inW, inb, lnkg, lnkb, Kf, Vf);

  for (int pt0 = 0; pt0 < NTOT; pt0 += NC){
    int nc = NTOT - pt0; if (nc > NC) nc = NC;
    int nb64 = nc / 64, np4 = nc / 4;
    hidden_h<<<np4,256,0,stream>>>(coords, qpW1, qpb1, S0, pt0);
    gemm4_k<1,1><<<nb64,256,0,stream>>>(S0, nullptr, Wqp2, nullptr, qpb2, lnqg, lnqb,
                                        nullptr, nullptr, nullptr, nullptr, nullptr, 0, 0, S1);
    gemm4_k<0,1><<<nb64,256,0,stream>>>(S1, nullptr, Wq, nullptr, inb, nullptr, nullptr,
                                        nullptr, nullptr, nullptr, nullptr, nullptr, 0, 0, S2);
    attn4_k<<<nb64,512,0,stream>>>(S2, Kf, Vf, S0, pt0);
    gemm4_k<0,1><<<nb64,256,0,stream>>>(S0, nullptr, Wout, nullptr, outb, nullptr, nullptr,
                                        nullptr, nullptr, nullptr, nullptr, nullptr, 0, 0, S1);
    gemm4_k<2,1><<<nb64,256,0,stream>>>(S1, nullptr, Wn2, nullptr, nullptr, nullptr, nullptr,
                                        coords, gW, gb, gmu, gg, pt0, 0, S0);
    ushort_t* xa = S0; ushort_t* xb = S2;
    for (int i = 1; i <= 4; ++i){
      gemm4_k<2,2><<<nb64,256,0,stream>>>(xa, S1, Wn1 + (size_t)(i-1)*131072, Wn2 + (size_t)i*131072,
                                          n1b + (size_t)(i-1)*256, nullptr, nullptr,
                                          coords, gW, gb, gmu, gg, pt0, i, xb);
      ushort_t* tmp = xa; xa = xb; xb = tmp;
    }
    fin_h<<<nb64,256,0,stream>>>(xa, finW, finb, outp, pt0);
  }
}

// Round 11
// 2285.276 us; speedup vs baseline: 1.4580x; 1.4580x over previous
//
#include <hip/hip_runtime.h>
#include <math.h>

#define NTOT 131072   // B*N

typedef unsigned short ushort_t;
typedef __attribute__((ext_vector_type(8))) short short8;
typedef __attribute__((ext_vector_type(4))) float f32x4;

__device__ __forceinline__ float bf2f(ushort_t u){
  unsigned int v = ((unsigned int)u) << 16; float f;
  __builtin_memcpy(&f, &v, 4); return f;
}
__device__ __forceinline__ ushort_t f2bf(float f){
  unsigned int x; __builtin_memcpy(&x, &f, 4);
  x = (x + 0x7fffu + ((x >> 16) & 1u)) >> 16;
  return (ushort_t)x;
}
__device__ __forceinline__ void gld16(const void* g, void* l){
  __builtin_amdgcn_global_load_lds((const __attribute__((address_space(1))) void*)g,
                                   (__attribute__((address_space(3))) void*)l, 16, 0, 0);
}

// ---------------- weight packing: hi/lo planes ----------------
__global__ __launch_bounds__(256) void packhl_k(const float* __restrict__ src, ushort_t* __restrict__ dst, int n){
  int i = blockIdx.x*256 + threadIdx.x;
  if (i < n){
    float v = src[i];
    ushort_t hi = f2bf(v);
    dst[i] = hi;
    dst[n + i] = f2bf(v - bf2f(hi));
  }
}

// ---------------- KV prep: LN(z_multi) -> K, V (f32, [b][m][256]) ----------------
__global__ __launch_bounds__(256) void prepkv_f(const float* __restrict__ zm, const float* __restrict__ inW,
    const float* __restrict__ inb, const float* __restrict__ g, const float* __restrict__ bv,
    float* __restrict__ Kf, float* __restrict__ Vf){
  __shared__ float zr[256];
  __shared__ float red[256];
  int bm = blockIdx.x;
  int t = threadIdx.x;
  float v = zm[(size_t)bm*256 + t];
  red[t] = v; __syncthreads();
  for (int s = 128; s > 0; s >>= 1){ if (t < s) red[t] += red[t+s]; __syncthreads(); }
  float mu = red[0] * (1.f/256.f); __syncthreads();
  red[t] = (v-mu)*(v-mu); __syncthreads();
  for (int s = 128; s > 0; s >>= 1){ if (t < s) red[t] += red[t+s]; __syncthreads(); }
  float var = red[0] * (1.f/256.f);
  float rsd = rsqrtf(var + 1e-5f);
  __syncthreads();
  zr[t] = (v - mu) * rsd * g[t] + bv[t];
  __syncthreads();
  float accK = inb[256+t], accV = inb[512+t];
  const float* wk = inW + (size_t)(256+t)*256;
  const float* wv = inW + (size_t)(512+t)*256;
  for (int d = 0; d < 256; d += 4){
    float4 a = *(const float4*)(zr + d);
    float4 k4 = *(const float4*)(wk + d);
    float4 v4 = *(const float4*)(wv + d);
    accK += a.x*k4.x + a.y*k4.y + a.z*k4.z + a.w*k4.w;
    accV += a.x*v4.x + a.y*v4.y + a.z*v4.z + a.w*v4.w;
  }
  Kf[(size_t)bm*256 + t] = accK;
  Vf[(size_t)bm*256 + t] = accV;
}

// ---------------- coord MLP first layer: GELU(x0@W1^T+b1), f32 out ----------------
__global__ __launch_bounds__(256) void hidden_f(const float* __restrict__ coords, const float* __restrict__ W1,
    const float* __restrict__ b1, float* __restrict__ out, int pt0){
  int h = threadIdx.x; int p0 = blockIdx.x*4;
  float w0 = W1[h*2], w1 = W1[h*2+1], bb = b1[h];
  #pragma unroll
  for (int pp = 0; pp < 4; ++pp){
    size_t gpt = (size_t)(pt0 + p0 + pp);
    float x = coords[gpt*2], y = coords[gpt*2+1];
    float v = x*w0 + y*w1 + bb;
    out[(size_t)(p0+pp)*256 + h] = 0.5f * v * (1.f + erff(v * 0.70710678118654752f));
  }
}

// ---------------- 3-term hi/lo MFMA GEMM, BM=64, 256 threads (4 waves) ----------------
// out[row][col] = sum_k A[row][k]*W[col][k] (+bias); W packed bf16 hi plane then lo.
// EPI 0: plain  1: LayerNorm  2: multiply gabor basis computed in epilogue.
// NPASS 2: also accumulate A1 x W1.
__device__ __forceinline__ void stage_w32(const ushort_t* Wbase, int oc, ushort_t* dsth, ushort_t* dstl, int w, int lane){
  #pragma unroll
  for (int part = 0; part < 2; ++part){
    const char* src0 = (const char*)(Wbase + part*65536);
    char* dst = (char*)(part ? dstl : dsth);
    #pragma unroll
    for (int i = 0; i < 4; ++i){
      int flat = ((w*4+i)*64 + lane)*16;
      int row = flat >> 9, kb = flat & 511;
      int skb = kb ^ ((row & 31) << 4);
      gld16(src0 + (size_t)(oc*32+row)*512 + skb, dst + (size_t)(w*4+i)*1024);
    }
  }
}

__device__ __forceinline__ void split_frags(const float* Ar, short8* ah, short8* al, int q4){
  #pragma unroll
  for (int kc = 0; kc < 8; ++kc){
    const float* p = Ar + kc*32 + q4*8;
    short8 h8, l8;
    #pragma unroll
    for (int j = 0; j < 8; ++j){
      float v = p[j];
      ushort_t hi = f2bf(v);
      h8[j] = (short)hi;
      l8[j] = (short)f2bf(v - bf2f(hi));
    }
    ah[kc] = h8; al[kc] = l8;
  }
}

template<int EPI, int NPASS>
__global__ __launch_bounds__(256) void gemm3f_k(const float* __restrict__ A0,
    const float* __restrict__ A1, const ushort_t* __restrict__ W0,
    const ushort_t* __restrict__ W1, const float* __restrict__ bias,
    const float* __restrict__ lng, const float* __restrict__ lnb,
    const float* __restrict__ coords, const float* __restrict__ gW,
    const float* __restrict__ gb, const float* __restrict__ gmu,
    const float* __restrict__ gg, int pt0g, int fidx,
    float* __restrict__ outp){
  __shared__ ushort_t Whs[2][32*256];
  __shared__ ushort_t Wls[2][32*256];
  const int tid = threadIdx.x, lane = tid & 63, w = tid >> 6;
  const int r16 = lane & 15, q4 = lane >> 4;
  const int row0 = blockIdx.x * 64;
  const size_t arow = (size_t)(row0 + w*16 + r16);

  short8 ah[8], al[8];
  split_frags(A0 + arow*256, ah, al, q4);
  stage_w32(W0, 0, Whs[0], Wls[0], w, lane);

  f32x4 acc[16];
  #pragma unroll
  for (int i = 0; i < 16; ++i) acc[i] = (f32x4){0.f,0.f,0.f,0.f};
  __syncthreads();

  constexpr int TCH = NPASS*8;
  for (int t = 0; t < TCH; ++t){
    const int buf = t & 1;
    if (t + 1 < TCH){
      const int tn = t + 1;
      stage_w32((tn >= 8) ? W1 : W0, tn & 7, Whs[tn&1], Wls[tn&1], w, lane);
    }
    if constexpr (NPASS == 2){
      if (t == 8) split_frags(A1 + arow*256, ah, al, q4);
    }
    const int oc = t & 7;
    const char* Bh = (const char*)Whs[buf];
    const char* Bl = (const char*)Wls[buf];
    #pragma unroll
    for (int kc = 0; kc < 8; ++kc){
      const int koff = (kc*32 + q4*8)*2;
      #pragma unroll
      for (int cg = 0; cg < 2; ++cg){
        const int wrow = cg*16 + r16;
        const int off = koff ^ ((wrow & 31) << 4);
        short8 bh = *(const short8*)(Bh + (size_t)wrow*512 + off);
        short8 bl = *(const short8*)(Bl + (size_t)wrow*512 + off);
        f32x4 a_ = acc[oc*2+cg];
        a_ = __builtin_amdgcn_mfma_f32_16x16x32_bf16(ah[kc], bh, a_, 0, 0, 0);
        a_ = __builtin_amdgcn_mfma_f32_16x16x32_bf16(al[kc], bh, a_, 0, 0, 0);
        a_ = __builtin_amdgcn_mfma_f32_16x16x32_bf16(ah[kc], bl, a_, 0, 0, 0);
        acc[oc*2+cg] = a_;
      }
    }
    __syncthreads();
  }

  const int crow = row0 + w*16 + q4*4;
  if (bias){
    #pragma unroll
    for (int idx = 0; idx < 16; ++idx){
      const int col = (idx>>1)*32 + (idx&1)*16 + r16;
      const float bb = bias[col];
      #pragma unroll
      for (int r = 0; r < 4; ++r) acc[idx][r] += bb;
    }
  }
  if constexpr (EPI == 1){
    float mu[4], rs[4];
    #pragma unroll
    for (int r = 0; r < 4; ++r){
      float s = 0.f, s2 = 0.f;
      #pragma unroll
      for (int idx = 0; idx < 16; ++idx){ float v = acc[idx][r]; s += v; s2 += v*v; }
      #pragma unroll
      for (int m = 1; m < 16; m <<= 1){ s += __shfl_xor(s, m); s2 += __shfl_xor(s2, m); }
      float mean = s * (1.f/256.f);
      float var = s2 * (1.f/256.f) - mean*mean;
      mu[r] = mean; rs[r] = rsqrtf(var + 1e-5f);
    }
    #pragma unroll
    for (int idx = 0; idx < 16; ++idx){
      const int col = (idx>>1)*32 + (idx&1)*16 + r16;
      const float gv = lng[col], bv = lnb[col];
      #pragma unroll
      for (int r = 0; r < 4; ++r)
        outp[(size_t)(crow + r)*256 + col] = (acc[idx][r] - mu[r]) * rs[r] * gv + bv;
    }
  } else if constexpr (EPI == 2){
    float xs[4], ys[4], xx[4];
    #pragma unroll
    for (int r = 0; r < 4; ++r){
      size_t gp = (size_t)(pt0g + crow + r);
      float x = coords[gp*2], y = coords[gp*2+1];
      xs[r] = x; ys[r] = y; xx[r] = x*x + y*y;
    }
    #pragma unroll
    for (int idx = 0; idx < 16; ++idx){
      const int col = (idx>>1)*32 + (idx&1)*16 + r16;
      const int o = fidx*256 + col;
      const float w0 = gW[o*2], w1 = gW[o*2+1];
      const float m0 = gmu[o*2], m1 = gmu[o*2+1];
      const float bb = gb[o], ga = gg[o];
      const float mm = m0*m0 + m1*m1;
      #pragma unroll
      for (int r = 0; r < 4; ++r){
        float D = xx[r] + mm - 2.f*(xs[r]*m0 + ys[r]*m1);
        float bas = sinf(xs[r]*w0 + ys[r]*w1 + bb) * expf(-0.5f * D * ga);
        outp[(size_t)(crow + r)*256 + col] = acc[idx][r] * bas;
      }
    }
  } else {
    #pragma unroll
    for (int idx = 0; idx < 16; ++idx){
      const int col = (idx>>1)*32 + (idx&1)*16 + r16;
      #pragma unroll
      for (int r = 0; r < 4; ++r)
        outp[(size_t)(crow + r)*256 + col] = acc[idx][r];
    }
  }
}

// ---------------- attention: two-pass VALU with K,V staged in LDS ----------------
// Block: 512 threads = 64 points x 8 heads. Thread = (p = tid&63, h = tid>>6).
// K,V for the block's batch staged in LDS (128 KB); all K/V reads wave-uniform.
__global__ __launch_bounds__(512) void attn3_k(const float* __restrict__ Q,
    const float* __restrict__ Kf, const float* __restrict__ Vf,
    float* __restrict__ ctx, int pt0){
  __shared__ float Kl[64*256];
  __shared__ float Vl[64*256];
  const int tid = threadIdx.x;
  const int p = tid & 63, h = tid >> 6;
  const int prow0 = blockIdx.x * 64;
  const int b = (pt0 + prow0) >> 14;
  {
    const float4* Kg = (const float4*)(Kf + (size_t)b*64*256);
    const float4* Vg = (const float4*)(Vf + (size_t)b*64*256);
    float4* Klv = (float4*)Kl;
    float4* Vlv = (float4*)Vl;
    #pragma unroll
    for (int i = 0; i < 8; ++i){
      int ix = i*512 + tid;
      Klv[ix] = Kg[ix];
      Vlv[ix] = Vg[ix];
    }
  }
  __syncthreads();

  const size_t qrow = (size_t)(prow0 + p)*256 + h*32;
  const float scale = 0.17677669529663687f;
  float q[32];
  #pragma unroll
  for (int k4 = 0; k4 < 32; k4 += 4){
    float4 qv = *(const float4*)(Q + qrow + k4);
    q[k4] = qv.x; q[k4+1] = qv.y; q[k4+2] = qv.z; q[k4+3] = qv.w;
  }
  // pass 1: row max
  float mx = -1e30f;
  #pragma unroll 4
  for (int m = 0; m < 64; ++m){
    const float* Kr = Kl + m*256 + h*32;
    float s = 0.f;
    #pragma unroll
    for (int k4 = 0; k4 < 32; k4 += 4){
      float4 kv = *(const float4*)(Kr + k4);
      s += q[k4]*kv.x + q[k4+1]*kv.y + q[k4+2]*kv.z + q[k4+3]*kv.w;
    }
    mx = fmaxf(mx, s*scale);
  }
  // pass 2: exp, sum, PV
  float o[32];
  #pragma unroll
  for (int d = 0; d < 32; ++d) o[d] = 0.f;
  float sum = 0.f;
  #pragma unroll 2
  for (int m = 0; m < 64; ++m){
    const float* Kr = Kl + m*256 + h*32;
    float s = 0.f;
    #pragma unroll
    for (int k4 = 0; k4 < 32; k4 += 4){
      float4 kv = *(const float4*)(Kr + k4);
      s += q[k4]*kv.x + q[k4+1]*kv.y + q[k4+2]*kv.z + q[k4+3]*kv.w;
    }
    float pe = __expf(s*scale - mx);
    sum += pe;
    const float* Vr = Vl + m*256 + h*32;
    #pragma unroll
    for (int d4 = 0; d4 < 32; d4 += 4){
      float4 vv = *(const float4*)(Vr + d4);
      o[d4] += pe*vv.x; o[d4+1] += pe*vv.y; o[d4+2] += pe*vv.z; o[d4+3] += pe*vv.w;
    }
  }
  const float inv = 1.f / sum;
  #pragma unroll
  for (int d4 = 0; d4 < 32; d4 += 4){
    float4 ov;
    ov.x = o[d4]*inv; ov.y = o[d4+1]*inv; ov.z = o[d4+2]*inv; ov.w = o[d4+3]*inv;
    *(float4*)(ctx + qrow + d4) = ov;
  }
}

// ---------------- fin GEMM (36x256, f32) + irfft head ----------------
__global__ __launch_bounds__(256) void fin_f(const float* __restrict__ X, const float* __restrict__ fW,
    const float* __restrict__ fb, float* __restrict__ outp, int pt0){
  __shared__ float Xl[64][260];
  __shared__ float s36p[64][4][37];
  __shared__ float ctab[7][16];
  __shared__ float stab[7][16];
  const int tid = threadIdx.x;
  const int row0 = blockIdx.x * 64;
  if (tid < 112){
    int f = tid >> 4, t = tid & 15;
    float a = 3.14159265358979323846f * (float)((f+1)*t) / 8.f;
    float s, c; sincosf(a, &s, &c);
    ctab[f][t] = c; stab[f][t] = s;
  }
  #pragma unroll
  for (int i = 0; i < 16; ++i){
    int r = i*4 + (tid >> 6);
    *(float4*)(&Xl[r][(tid&63)*4]) = *(const float4*)(X + (size_t)(row0 + r)*256 + (tid&63)*4);
  }
  __syncthreads();
  {
    const int p = tid & 63, g = tid >> 6;
    float xs[64];
    #pragma unroll
    for (int k4 = 0; k4 < 64; k4 += 4){
      float4 xv = *(const float4*)(&Xl[p][g*64 + k4]);
      xs[k4] = xv.x; xs[k4+1] = xv.y; xs[k4+2] = xv.z; xs[k4+3] = xv.w;
    }
    #pragma unroll
    for (int c = 0; c < 36; ++c){
      const float* Wr = fW + (size_t)c*256 + g*64;
      float s = 0.f;
      #pragma unroll
      for (int k4 = 0; k4 < 64; k4 += 4){
        float4 wv = *(const float4*)(Wr + k4);
        s += xs[k4]*wv.x + xs[k4+1]*wv.y + xs[k4+2]*wv.z + xs[k4+3]*wv.w;
      }
      s36p[p][g][c] = s;
    }
  }
  __syncthreads();

  const int pl = tid & 63, tg = tid >> 6;
  const int gpt = pt0 + row0 + pl;
  const int b = gpt >> 14; const int n = gpt & 16383;
  float R[36];
  #pragma unroll
  for (int i = 0; i < 36; ++i)
    R[i] = s36p[pl][0][i] + s36p[pl][1][i] + s36p[pl][2][i] + s36p[pl][3][i] + fb[i];
  #pragma unroll
  for (int tt = 0; tt < 4; ++tt){
    int t = tg*4 + tt;
    float o0 = 0.f, o1 = 0.f;
    #pragma unroll
    for (int c = 0; c < 2; ++c){
      float v = R[c*2] + ((t & 1) ? -R[32 + c*2] : R[32 + c*2]);
      #pragma unroll
      for (int f = 1; f < 8; ++f){
        v += 2.f * (R[f*4 + c*2] * ctab[f-1][t] - R[f*4 + c*2 + 1] * stab[f-1][t]);
      }
      v *= 0.25f;
      if (c == 0) o0 = v; else o1 = v;
    }
    float2 wv; wv.x = o0; wv.y = o1;
    *(float2*)(outp + ((size_t)(b*16 + t)*16384 + n)*2) = wv;
  }
}

// ---------------- host ----------------
extern "C" void kernel_launch(void* const* d_in, const int* in_sizes, int n_in,
                              void* d_out, int out_size, void* d_ws, size_t ws_size,
                              hipStream_t stream){
  const float* z_multi=(const float*)d_in[0];
  const float* coords =(const float*)d_in[1];
  const float* gW =(const float*)d_in[2];
  const float* gb =(const float*)d_in[3];
  const float* gmu=(const float*)d_in[4];
  const float* gg =(const float*)d_in[5];
  const float* n1W=(const float*)d_in[6];
  const float* n1b=(const float*)d_in[7];
  const float* n2W=(const float*)d_in[8];
  const float* qpW1=(const float*)d_in[9];
  const float* qpb1=(const float*)d_in[10];
  const float* qpW2=(const float*)d_in[11];
  const float* qpb2=(const float*)d_in[12];
  const float* inW=(const float*)d_in[13];
  const float* inb=(const float*)d_in[14];
  const float* outW=(const float*)d_in[15];
  const float* outb=(const float*)d_in[16];
  const float* lnqg=(const float*)d_in[17];
  const float* lnqb=(const float*)d_in[18];
  const float* lnkg=(const float*)d_in[19];
  const float* lnkb=(const float*)d_in[20];
  const float* finW=(const float*)d_in[21];
  const float* finb=(const float*)d_in[22];
  float* outp=(float*)d_out;
  char* ws=(char*)d_ws;

  ushort_t* Wqp2=(ushort_t*)(ws + 0);         // 262144 B each (hi+lo planes)
  ushort_t* Wq  =(ushort_t*)(ws + 262144);
  ushort_t* Wout=(ushort_t*)(ws + 524288);
  ushort_t* Wn2 =(ushort_t*)(ws + 786432);    // 5 x 262144 -> ends 2097152
  ushort_t* Wn1 =(ushort_t*)(ws + 2097152);   // 4 x 262144 -> ends 3145728
  float* Kf = (float*)(ws + 3145728);         // 512 KB
  float* Vf = (float*)(ws + 3670016);         // 512 KB
  const size_t BASE = 4194304;
  size_t avail = (ws_size > BASE) ? (ws_size - BASE) : 0;
  long long ncl = (long long)(avail / 3072) & ~127LL;
  if (ncl < 128) ncl = 128;
  if (ncl > 32768) ncl = 32768;   // cap: keep S0+S1+S2 (96 MB) L3-resident
  const int NC = (int)ncl;
  float* S0 = (float*)(ws + BASE);
  float* S1 = S0 + (size_t)NC*256;
  float* S2 = S1 + (size_t)NC*256;

  packhl_k<<<256,256,0,stream>>>(qpW2, Wqp2, 65536);
  packhl_k<<<256,256,0,stream>>>(inW,  Wq,   65536);
  packhl_k<<<256,256,0,stream>>>(outW, Wout, 65536);
  for (int l = 0; l < 5; ++l)
    packhl_k<<<256,256,0,stream>>>(n2W + (size_t)l*65536, Wn2 + (size_t)l*131072, 65536);
  for (int l = 0; l < 4; ++l)
    packhl_k<<<256,256,0,stream>>>(n1W + (size_t)l*65536, Wn1 + (size_t)l*131072, 65536);
  prepkv_f<<<512,256,0,stream>>>(z_multi, inW, inb, lnkg, lnkb, Kf, Vf);

  for (int pt0 = 0; pt0 < NTOT; pt0 += NC){
    int nc = NTOT - pt0; if (nc > NC) nc = NC;
    int nb64 = nc / 64, np4 = nc / 4;
    hidden_f<<<np4,256,0,stream>>>(coords, qpW1, qpb1, S0, pt0);
    gemm3f_k<1,1><<<nb64,256,0,stream>>>(S0, nullptr, Wqp2, nullptr, qpb2, lnqg, lnqb,
                                         nullptr, nullptr, nullptr, nullptr, nullptr, 0, 0, S1);
    gemm3f_k<0,1><<<nb64,256,0,stream>>>(S1, nullptr, Wq, nullptr, inb, nullptr, nullptr,
                                         nullptr, nullptr, nullptr, nullptr, nullptr, 0, 0, S2);
    attn3_k<<<nb64,512,0,stream>>>(S2, Kf, Vf, S0, pt0);
    gemm3f_k<0,1><<<nb64,256,0,stream>>>(S0, nullptr, Wout, nullptr, outb, nullptr, nullptr,
                                         nullptr, nullptr, nullptr, nullptr, nullptr, 0, 0, S1);
    gemm3f_k<2,1><<<nb64,256,0,stream>>>(S1, nullptr, Wn2, nullptr, nullptr, nullptr, nullptr,
                                         coords, gW, gb, gmu, gg, pt0, 0, S0);
    float* xa = S0; float* xb = S2;
    for (int i = 1; i <= 4; ++i){
      gemm3f_k<2,2><<<nb64,256,0,stream>>>(xa, S1, Wn1 + (size_t)(i-1)*131072, Wn2 + (size_t)i*131072,
                                           n1b + (size_t)(i-1)*256, nullptr, nullptr,
                                           coords, gW, gb, gmu, gg, pt0, i, xb);
      float* tmp = xa; xa = xb; xb = tmp;
    }
    fin_f<<<nb64,256,0,stream>>>(xa, finW, finb, outp, pt0);
  }
}